// Round 8
// baseline (236052.466 us; speedup 1.0000x reference)
//
#include <hip/hip_runtime.h>
#include <stdint.h>

typedef float    f32x4  __attribute__((ext_vector_type(4)));
typedef short    short8 __attribute__((ext_vector_type(8)));
typedef uint32_t u32x4  __attribute__((ext_vector_type(4)));

__device__ inline uint16_t f2bf(float f){
  uint32_t u = __float_as_uint(f);
  u += 0x7fffu + ((u >> 16) & 1u);   // RNE
  return (uint16_t)(u >> 16);
}

// ---------------- prepack: weights -> per-WG MFMA B-fragment records ----------------
// record = 1KB: 64 lanes x 16B; lane l holds W[kbase+(l>>4)*8+j][colbase+(l&15)], j=0..7
struct PreP {
  const float *Wdh0,*Wzh0,*Wmup0,*Wsgp0,*Wdh1,*Wzh1,*Wih1,*Wmup1,*Wsgp1,*Wout;
  uint32_t* dst;
};

__global__ __launch_bounds__(64) void prepack(PreP P){
  const int rec = blockIdx.x, l = threadIdx.x;
  int role, s, r;
  if (rec < 832){ role = 0; s = rec / 52; r = rec % 52; }
  else          { role = 1; int rr = rec - 832; s = rr / 82; r = rr % 82; }
  const int cl = l & 15, kb = (l >> 4) * 8;
  float v[8];
#pragma unroll
  for (int j = 0; j < 8; ++j) v[j] = 0.f;
  if (role == 0){
    if (r < 48){
      int n = r >> 4, k = r & 15, c = 16*n + cl, kk0 = k*32 + kb;
      if (c < 32){ int col = 32*s + c;
#pragma unroll
        for (int j = 0; j < 8; ++j) v[j] = P.Wdh0[(size_t)(kk0+j)*512 + col];
      } else if (c < 36){ int col = 4*s + (c-32);
#pragma unroll
        for (int j = 0; j < 8; ++j) v[j] = P.Wmup0[(size_t)(kk0+j)*64 + col];
      } else if (c < 40){ int col = 4*s + (c-36);
#pragma unroll
        for (int j = 0; j < 8; ++j) v[j] = P.Wsgp0[(size_t)(kk0+j)*64 + col];
      }
    } else {
      int r2 = r - 48, n = r2 >> 1, k = r2 & 1, col = 32*s + 16*n + cl, kk0 = k*32 + kb;
#pragma unroll
      for (int j = 0; j < 8; ++j) v[j] = P.Wzh0[(size_t)(kk0+j)*512 + col];
    }
  } else {
    if (r < 48){
      int n = r >> 4, k = r & 15, c = 16*n + cl, kk0 = k*32 + kb;
      if (c < 32){ int col = 32*s + c;
#pragma unroll
        for (int j = 0; j < 8; ++j) v[j] = P.Wdh1[(size_t)(kk0+j)*512 + col];
      } else if (c < 34){ int col = 2*s + (c-32);
#pragma unroll
        for (int j = 0; j < 8; ++j) v[j] = P.Wmup1[(size_t)(kk0+j)*32 + col];
      } else if (c < 36){ int col = 2*s + (c-34);
#pragma unroll
        for (int j = 0; j < 8; ++j) v[j] = P.Wsgp1[(size_t)(kk0+j)*32 + col];
      } else if (c < 40){ int col = 4*s + (c-36);
#pragma unroll
        for (int j = 0; j < 8; ++j) v[j] = P.Wout[(size_t)(kk0+j)*64 + col];
      }
    } else if (r < 80){
      int r2 = r - 48, n = r2 >> 4, k = r2 & 15, col = 32*s + 16*n + cl, kk0 = k*32 + kb;
#pragma unroll
      for (int j = 0; j < 8; ++j) v[j] = P.Wih1[(size_t)(kk0+j)*512 + col];
    } else {
      int n = r - 80, col = 32*s + 16*n + cl;
#pragma unroll
      for (int j = 0; j < 8; ++j) v[j] = P.Wzh1[(size_t)(kb+j)*512 + col];
    }
  }
  u32x4 o;
  o.x = (uint32_t)f2bf(v[0]) | ((uint32_t)f2bf(v[1]) << 16);
  o.y = (uint32_t)f2bf(v[2]) | ((uint32_t)f2bf(v[3]) << 16);
  o.z = (uint32_t)f2bf(v[4]) | ((uint32_t)f2bf(v[5]) << 16);
  o.w = (uint32_t)f2bf(v[6]) | ((uint32_t)f2bf(v[7]) << 16);
  ((u32x4*)(P.dst + (size_t)rec * 256))[l] = o;
}

// ---- XCD-local (L2) transport: sc0 = bypass L1, stay in this XCD's L2 ----
__device__ inline void gld4(u32x4* a, const short* base){
  asm volatile("global_load_dwordx4 %0, %4, off sc0\n\t"
               "global_load_dwordx4 %1, %4, off offset:1024 sc0\n\t"
               "global_load_dwordx4 %2, %4, off offset:2048 sc0\n\t"
               "global_load_dwordx4 %3, %4, off offset:3072 sc0"
               : "=v"(a[0]), "=v"(a[1]), "=v"(a[2]), "=v"(a[3])
               : "v"(base) : "memory");
}
__device__ inline void l2_store16(short* dst, u32x4 v){
  asm volatile("global_store_dwordx4 %0, %1, off sc0" :: "v"(dst), "v"(v) : "memory");
}
__device__ inline int l2_poll(const int* p){
  int v;
  asm volatile("global_load_dword %0, %1, off sc0\n\ts_waitcnt vmcnt(0)"
               : "=v"(v) : "v"(p) : "memory");
  return v;
}
__device__ inline void l2_inc(int* p){
  int one = 1;
  asm volatile("global_atomic_add %0, %1, off" :: "v"(p), "v"(one) : "memory");
}
__device__ inline void vm_drain(){
  asm volatile("s_waitcnt vmcnt(0)" ::: "memory");
}

// ---------------- pipelined scan: 8 groups x 16 rows, L0+L1 co-located per XCD ----------------
struct ScanP {
  const short* wrec;
  short* pub;                                    // [layer2][ring4][group8][16KB records]
  int *ctrA, *ctrB;
  int cs;
  const float *bh0,*bmup0,*bsgp0,*bh1,*bmup1,*bsgp1,*bout;
  const float *Am0,*As0,*E0,*Am1,*As1,*E1;
  float *out, *klpart;
};

__global__ __launch_bounds__(192, 1) void pvrnn_scan(ScanP P){
  extern __shared__ char smem[];
  short* ldsW  = (short*)smem;                   // up to 82 recs * 1KB
  short* zbS   = (short*)(smem + 83968);         // [3][16][72] bf16
  float* muqS  = (float*)(smem + 90880);         // [3][16][64] f32
  float* tqS   = (float*)(smem + 103168);        // [3][16][64] f32
  short* dtile = (short*)(smem + 115456);        // [16][40] bf16 (padded)
  float* mupT  = (float*)(smem + 116736);        // [16][4]
  float* tpT   = (float*)(smem + 116992);        // [16][4]
  float* xT    = (float*)(smem + 117248);        // [16][4] (end 117504)

  const int p = blockIdx.x;
  const int g = p & 7;                            // group == XCD (round-robin dispatch)
  const int q = p >> 3;                           // 0..31 within XCD
  const int role = q >> 4;                        // 0=L0, 1=L1
  const int s = q & 15;                           // slice
  const int wid = g*32 + role*16 + s;

  const int tid = threadIdx.x;
  const int l = tid & 63, w = tid >> 6;           // waves 0,1 = recurrent n; 2 = heads
  const int c = l & 15, kb8 = (l >> 4) * 8;
  const int CW = role ? 32 : 64;
  const int sh = role ? 5 : 6;
  const int CS = P.cs;

  { // weights -> LDS
    const u32x4* src = (const u32x4*)(P.wrec + (size_t)(role ? (832 + s*82) : (s*52)) * 512);
    const int n16 = (role ? 82 : 52) * 64;
    for (int i = tid; i < n16; i += 192) ((u32x4*)ldsW)[i] = src[i];
  }
  float bias_rec = 0.f, bias_head = 0.f;
  if (w < 2){
    bias_rec = role ? P.bh1[32*s + 16*w + c] : P.bh0[32*s + 16*w + c];
  } else {
    if (!role){
      if (c < 4)      bias_head = P.bmup0[4*s + c];
      else if (c < 8) bias_head = P.bsgp0[4*s + c - 4];
    } else {
      if (c < 2)      bias_head = P.bmup1[2*s + c];
      else if (c < 4) bias_head = P.bsgp1[2*s + c - 2];
      else if (c < 8) bias_head = P.bout [4*s + c - 4];
    }
  }
  const float* AM = role ? P.Am1 : P.Am0;
  const float* AS = role ? P.As1 : P.As0;
  const float* EP = role ? P.E1  : P.E0;

  auto do_stats = [&](int tt){                    // threads 64..191 only
    const int par2 = tt % 3;
    const int NE = 16 << sh;
    for (int idx = tid - 64; idx < NE; idx += 128){
      int rr = idx >> sh, cc = idx & (CW - 1);
      size_t sidx = ((size_t)(16*g + rr) * 2048 + tt) * CW + cc;
      float mq = tanhf(AM[sidx]);
      float tq = tanhf(AS[sidx]);
      muqS[par2*1024 + rr*64 + cc] = mq;
      tqS [par2*1024 + rr*64 + cc] = tq;
      zbS [par2*1152 + rr*72 + cc] = (short)f2bf(fmaf(__expf(tq), EP[sidx], mq));
    }
  };
  if (w >= 1) do_stats(0);
  __syncthreads();

  float h[4] = {0.f,0.f,0.f,0.f};
  float klacc = 0.f;
  bool dead = false;
  short* pubL0 = P.pub;                           // L0 region: 4*8*8192 shorts
  short* pubL1 = P.pub + 4*8*8192;
  short* pubSelf = role ? pubL1 : pubL0;
  int* myctr = (role ? P.ctrB : P.ctrA) + (size_t)g * 2048 * CS;
  int* otctr = (role ? P.ctrA : P.ctrB) + (size_t)g * 2048 * CS;
  const float leak = role ? 0.875f : 0.5f, gain = role ? 0.125f : 0.5f;

  for (int t = 0; t < 2048; ++t){
    if (tid == 0){
      auto spinw = [&](int* a){
        if (dead) return;
        int it = 0;
        while (l2_poll(a) < 16){
          __builtin_amdgcn_s_sleep(1);
          if (++it > 2000000){ dead = true; return; }
        }
      };
      if (!role){
        if (t >= 1) spinw(myctr + (size_t)(t-1)*CS);
        if (t >= 4) spinw(otctr + (size_t)(t-4)*CS);
      } else {
        spinw(otctr + (size_t)t*CS);
        if (t >= 1) spinw(myctr + (size_t)(t-1)*CS);
      }
    } else if (w >= 1 && t + 1 < 2048){
      do_stats(t + 1);
    }
    __syncthreads();                              // B1

    const int par = t % 3;
    const short* baseS = pubSelf + (size_t)((((t-1)&3)*8 + g)) * 8192 + l*8;
    u32x4 af[16];
    gld4(af+0,  baseS);        gld4(af+4,  baseS+2048);
    gld4(af+8,  baseS+4096);   gld4(af+12, baseS+6144);
    u32x4 ag[16];
    if (role && w < 2){
      const short* baseO = pubL0 + (size_t)(((t&3)*8 + g)) * 8192 + l*8;
      gld4(ag+0,  baseO);      gld4(ag+4,  baseO+2048);
      gld4(ag+8,  baseO+4096); gld4(ag+12, baseO+6144);
    }
    vm_drain();
    __builtin_amdgcn_sched_barrier(0);

    f32x4 av[4] = {{0.f,0.f,0.f,0.f},{0.f,0.f,0.f,0.f},{0.f,0.f,0.f,0.f},{0.f,0.f,0.f,0.f}};
    if (w < 2){
#pragma unroll
      for (int k = 0; k < 16; ++k){
        short8 b = *(const short8*)(ldsW + (w*16 + k)*512 + l*8);
        av[k&3] = __builtin_amdgcn_mfma_f32_16x16x32_bf16(*(const short8*)&af[k], b, av[k&3], 0,0,0);
      }
      if (role){
#pragma unroll
        for (int k = 0; k < 16; ++k){
          short8 b = *(const short8*)(ldsW + (48 + w*16 + k)*512 + l*8);
          av[k&3] = __builtin_amdgcn_mfma_f32_16x16x32_bf16(*(const short8*)&ag[k], b, av[k&3], 0,0,0);
        }
        short8 az = *(const short8*)(zbS + par*1152 + c*72 + kb8);
        short8 bz = *(const short8*)(ldsW + (80 + w)*512 + l*8);
        av[0] = __builtin_amdgcn_mfma_f32_16x16x32_bf16(az, bz, av[0], 0,0,0);
      } else {
        short8 az0 = *(const short8*)(zbS + par*1152 + c*72 + kb8);
        short8 az1 = *(const short8*)(zbS + par*1152 + c*72 + 32 + kb8);
        short8 bz0 = *(const short8*)(ldsW + (48 + w*2    )*512 + l*8);
        short8 bz1 = *(const short8*)(ldsW + (48 + w*2 + 1)*512 + l*8);
        av[0] = __builtin_amdgcn_mfma_f32_16x16x32_bf16(az0, bz0, av[0], 0,0,0);
        av[1] = __builtin_amdgcn_mfma_f32_16x16x32_bf16(az1, bz1, av[1], 0,0,0);
      }
    } else {
#pragma unroll
      for (int k = 0; k < 16; ++k){
        short8 b = *(const short8*)(ldsW + (32 + k)*512 + l*8);
        av[k&3] = __builtin_amdgcn_mfma_f32_16x16x32_bf16(*(const short8*)&af[k], b, av[k&3], 0,0,0);
      }
    }
    f32x4 acc = (av[0] + av[1]) + (av[2] + av[3]);

    // epilogue
    if (w < 2){
#pragma unroll
      for (int j = 0; j < 4; ++j){
        float pre = acc[j] + bias_rec;
        h[j] = leak*h[j] + gain*pre;
        int row = (l>>4)*4 + j;
        dtile[row*40 + 16*w + c] = (short)f2bf(tanhf(h[j]));
      }
    } else {
#pragma unroll
      for (int j = 0; j < 4; ++j){
        float pre = acc[j] + bias_head;
        int row = (l>>4)*4 + j;
        if (!role){
          if (c < 4)      mupT[row*4 + c]     = tanhf(pre);
          else if (c < 8) tpT [row*4 + c - 4] = tanhf(pre);
        } else {
          if (c < 2)      mupT[row*4 + c]     = tanhf(pre);
          else if (c < 4) tpT [row*4 + c - 2] = tanhf(pre);
          else if (c < 8) xT  [row*4 + c - 4] = 1.f/(1.f + __expf(-pre));
        }
      }
    }
    __syncthreads();                              // B2

    if (w == 0){                                  // publish record s (this slice's 32 cols)
      u32x4 v = *(const u32x4*)(dtile + c*40 + (l>>4)*8);
      short* dst = pubSelf + (size_t)(((t&3)*8 + g)) * 8192 + s*512 + l*8;
      l2_store16(dst, v);
      vm_drain();                                 // store committed to local L2
      if (l == 0) l2_inc(myctr + (size_t)t*CS);
    } else if (w == 2 && l < 16){
      if (role && t >= 1)
        *(float4*)(P.out + ((size_t)(16*g + l)*2048 + (t-1))*64 + 4*s)
          = *(const float4*)(xT + l*4);
      const int CC = role ? 2 : 4;
#pragma unroll
      for (int cc = 0; cc < 4; ++cc){
        if (cc < CC){
          float mp = mupT[l*4 + cc], tp = tpT[l*4 + cc];
          int zc = role ? (2*s + cc) : (4*s + cc);
          float mq = muqS[par*1024 + l*64 + zc];
          float tq = tqS [par*1024 + l*64 + zc];
          float dm = mq - mp;
          klacc += tp - tq + (__expf(2.f*tq) + dm*dm)*0.5f*__expf(-2.f*tp) - 0.5f;
        }
      }
    }
  }

  if (role){                                      // final x(2047) from d1(2047)
    if (tid == 0){
      int it = 0;
      while (!dead && l2_poll(myctr + (size_t)2047*CS) < 16){
        __builtin_amdgcn_s_sleep(1);
        if (++it > 2000000) dead = true;
      }
    }
    __syncthreads();
    if (w == 2){
      const short* baseS = pubL1 + (size_t)((3*8 + g)) * 8192 + l*8;
      u32x4 af[16];
      gld4(af+0,  baseS);        gld4(af+4,  baseS+2048);
      gld4(af+8,  baseS+4096);   gld4(af+12, baseS+6144);
      vm_drain();
      __builtin_amdgcn_sched_barrier(0);
      f32x4 av[4] = {{0.f,0.f,0.f,0.f},{0.f,0.f,0.f,0.f},{0.f,0.f,0.f,0.f},{0.f,0.f,0.f,0.f}};
#pragma unroll
      for (int k = 0; k < 16; ++k){
        short8 b = *(const short8*)(ldsW + (32 + k)*512 + l*8);
        av[k&3] = __builtin_amdgcn_mfma_f32_16x16x32_bf16(*(const short8*)&af[k], b, av[k&3], 0,0,0);
      }
      f32x4 acc = (av[0] + av[1]) + (av[2] + av[3]);
#pragma unroll
      for (int j = 0; j < 4; ++j){
        if (c >= 4 && c < 8){
          int row = (l>>4)*4 + j;
          xT[row*4 + c - 4] = 1.f/(1.f + __expf(-(acc[j] + bias_head)));
        }
      }
    }
    __syncthreads();
    if (w == 2 && l < 16)
      *(float4*)(P.out + ((size_t)(16*g + l)*2048 + 2047)*64 + 4*s)
        = *(const float4*)(xT + l*4);
  }

  if (w == 2){
    float v = klacc;
#pragma unroll
    for (int off = 32; off; off >>= 1) v += __shfl_down(v, off);
    if (l == 0) P.klpart[wid] = v;
  }
}

__global__ void kl_finalize(const float* __restrict__ klpart, float* __restrict__ out){
  if (blockIdx.x == 0 && threadIdx.x == 0){
    float k0 = 0.f, k1 = 0.f;
    for (int i = 0; i < 256; ++i){
      if ((i >> 4) & 1) k1 += klpart[i]; else k0 += klpart[i];
    }
    float kl = (k0 + k1) * (1.0f/128.0f);
    out[16777216] = kl;
    out[16777217] = 0.001f * kl;
  }
}

extern "C" void kernel_launch(void* const* d_in, const int* in_sizes, int n_in,
                              void* d_out, int out_size, void* d_ws, size_t ws_size,
                              hipStream_t stream){
  (void)in_sizes; (void)n_in; (void)out_size;
  const float* Wdh0  = (const float*)d_in[0];
  const float* Wzh0  = (const float*)d_in[1];
  const float* bh0   = (const float*)d_in[2];
  const float* Wmup0 = (const float*)d_in[3];
  const float* bmup0 = (const float*)d_in[4];
  const float* Wsgp0 = (const float*)d_in[5];
  const float* bsgp0 = (const float*)d_in[6];
  const float* Amu0  = (const float*)d_in[7];
  const float* Asg0  = (const float*)d_in[8];
  const float* Eps0  = (const float*)d_in[9];
  const float* Wdh1  = (const float*)d_in[10];
  const float* Wzh1  = (const float*)d_in[11];
  const float* Wih1  = (const float*)d_in[12];
  const float* bh1   = (const float*)d_in[13];
  const float* Wmup1 = (const float*)d_in[14];
  const float* bmup1 = (const float*)d_in[15];
  const float* Wsgp1 = (const float*)d_in[16];
  const float* bsgp1 = (const float*)d_in[17];
  const float* Amu1  = (const float*)d_in[18];
  const float* Asg1  = (const float*)d_in[19];
  const float* Eps1  = (const float*)d_in[20];
  const float* Wout  = (const float*)d_in[21];
  const float* bout  = (const float*)d_in[22];

  const size_t oW   = 0;                          // 2144 recs * 1KB = 2,195,456
  const size_t oPub = 2195456;                    // 2 layers * 4 ring * 8 groups * 16KB = 1 MB
  size_t fixed = oPub + 1048576;
  int cs = 16;
  size_t ctrbytes = (size_t)8 * 2048 * cs * 4;
  if (fixed + 2*ctrbytes + 1024 > ws_size){ cs = 4;  ctrbytes = (size_t)8*2048*cs*4; }
  if (fixed + 2*ctrbytes + 1024 > ws_size){ cs = 1;  ctrbytes = (size_t)8*2048*cs*4; }
  const size_t oCtrA = fixed;
  const size_t oCtrB = oCtrA + ctrbytes;
  const size_t oKL   = oCtrB + ctrbytes;
  const size_t total = oKL + 1024;
  if (ws_size < total) return;
  char* ws = (char*)d_ws;

  (void)hipMemsetAsync(ws + oPub, 0, total - oPub, stream);  // zero pub + counters + klpart

  PreP pp;
  pp.Wdh0 = Wdh0; pp.Wzh0 = Wzh0; pp.Wmup0 = Wmup0; pp.Wsgp0 = Wsgp0;
  pp.Wdh1 = Wdh1; pp.Wzh1 = Wzh1; pp.Wih1 = Wih1; pp.Wmup1 = Wmup1;
  pp.Wsgp1 = Wsgp1; pp.Wout = Wout; pp.dst = (uint32_t*)(ws + oW);
  prepack<<<dim3(2144), dim3(64), 0, stream>>>(pp);

  ScanP sp;
  sp.wrec = (const short*)(ws + oW);
  sp.pub  = (short*)(ws + oPub);
  sp.ctrA = (int*)(ws + oCtrA);
  sp.ctrB = (int*)(ws + oCtrB);
  sp.cs = cs;
  sp.bh0 = bh0; sp.bmup0 = bmup0; sp.bsgp0 = bsgp0;
  sp.bh1 = bh1; sp.bmup1 = bmup1; sp.bsgp1 = bsgp1; sp.bout = bout;
  sp.Am0 = Amu0; sp.As0 = Asg0; sp.E0 = Eps0;
  sp.Am1 = Amu1; sp.As1 = Asg1; sp.E1 = Eps1;
  sp.out = (float*)d_out;
  sp.klpart = (float*)(ws + oKL);

  const unsigned SMEM = 117504u;
  (void)hipFuncSetAttribute((const void*)pvrnn_scan,
                            hipFuncAttributeMaxDynamicSharedMemorySize, 131072);
  void* args[] = { &sp };
  if (hipLaunchCooperativeKernel((void*)pvrnn_scan, dim3(256), dim3(192),
                                 args, SMEM, stream) != hipSuccess){
    pvrnn_scan<<<dim3(256), dim3(192), SMEM, stream>>>(sp);
  }
  kl_finalize<<<1, 1, 0, stream>>>((const float*)(ws + oKL), (float*)d_out);
}

// Round 9
// 25750.211 us; speedup vs baseline: 9.1670x; 9.1670x over previous
//
#include <hip/hip_runtime.h>
#include <stdint.h>

typedef float    f32x4  __attribute__((ext_vector_type(4)));
typedef short    short8 __attribute__((ext_vector_type(8)));
typedef uint32_t u32x4  __attribute__((ext_vector_type(4)));

__device__ inline uint16_t f2bf(float f){
  uint32_t u = __float_as_uint(f);
  u += 0x7fffu + ((u >> 16) & 1u);   // RNE
  return (uint16_t)(u >> 16);
}

// ---------------- prepack: weights -> per-WG MFMA B-fragment records ----------------
// record = 1KB: 64 lanes x 16B; lane l holds W[kbase+(l>>4)*8+j][colbase+(l&15)], j=0..7
struct PreP {
  const float *Wdh0,*Wzh0,*Wmup0,*Wsgp0,*Wdh1,*Wzh1,*Wih1,*Wmup1,*Wsgp1,*Wout;
  uint32_t* dst;
};

__global__ __launch_bounds__(64) void prepack(PreP P){
  const int rec = blockIdx.x, l = threadIdx.x;
  int role, s, r;
  if (rec < 832){ role = 0; s = rec / 52; r = rec % 52; }
  else          { role = 1; int rr = rec - 832; s = rr / 82; r = rr % 82; }
  const int cl = l & 15, kb = (l >> 4) * 8;
  float v[8];
#pragma unroll
  for (int j = 0; j < 8; ++j) v[j] = 0.f;
  if (role == 0){
    if (r < 48){
      int n = r >> 4, k = r & 15, c = 16*n + cl, kk0 = k*32 + kb;
      if (c < 32){ int col = 32*s + c;
#pragma unroll
        for (int j = 0; j < 8; ++j) v[j] = P.Wdh0[(size_t)(kk0+j)*512 + col];
      } else if (c < 36){ int col = 4*s + (c-32);
#pragma unroll
        for (int j = 0; j < 8; ++j) v[j] = P.Wmup0[(size_t)(kk0+j)*64 + col];
      } else if (c < 40){ int col = 4*s + (c-36);
#pragma unroll
        for (int j = 0; j < 8; ++j) v[j] = P.Wsgp0[(size_t)(kk0+j)*64 + col];
      }
    } else {
      int r2 = r - 48, n = r2 >> 1, k = r2 & 1, col = 32*s + 16*n + cl, kk0 = k*32 + kb;
#pragma unroll
      for (int j = 0; j < 8; ++j) v[j] = P.Wzh0[(size_t)(kk0+j)*512 + col];
    }
  } else {
    if (r < 48){
      int n = r >> 4, k = r & 15, c = 16*n + cl, kk0 = k*32 + kb;
      if (c < 32){ int col = 32*s + c;
#pragma unroll
        for (int j = 0; j < 8; ++j) v[j] = P.Wdh1[(size_t)(kk0+j)*512 + col];
      } else if (c < 34){ int col = 2*s + (c-32);
#pragma unroll
        for (int j = 0; j < 8; ++j) v[j] = P.Wmup1[(size_t)(kk0+j)*32 + col];
      } else if (c < 36){ int col = 2*s + (c-34);
#pragma unroll
        for (int j = 0; j < 8; ++j) v[j] = P.Wsgp1[(size_t)(kk0+j)*32 + col];
      } else if (c < 40){ int col = 4*s + (c-36);
#pragma unroll
        for (int j = 0; j < 8; ++j) v[j] = P.Wout[(size_t)(kk0+j)*64 + col];
      }
    } else if (r < 80){
      int r2 = r - 48, n = r2 >> 4, k = r2 & 15, col = 32*s + 16*n + cl, kk0 = k*32 + kb;
#pragma unroll
      for (int j = 0; j < 8; ++j) v[j] = P.Wih1[(size_t)(kk0+j)*512 + col];
    } else {
      int n = r - 80, col = 32*s + 16*n + cl;
#pragma unroll
      for (int j = 0; j < 8; ++j) v[j] = P.Wzh1[(size_t)(kb+j)*512 + col];
    }
  }
  u32x4 o;
  o.x = (uint32_t)f2bf(v[0]) | ((uint32_t)f2bf(v[1]) << 16);
  o.y = (uint32_t)f2bf(v[2]) | ((uint32_t)f2bf(v[3]) << 16);
  o.z = (uint32_t)f2bf(v[4]) | ((uint32_t)f2bf(v[5]) << 16);
  o.w = (uint32_t)f2bf(v[6]) | ((uint32_t)f2bf(v[7]) << 16);
  ((u32x4*)(P.dst + (size_t)rec * 256))[l] = o;
}

// ---- device-coherent (LLC) transport: sc0 sc1 everywhere, no L2 residency games ----
__device__ inline void gld16(u32x4 (&a)[16], const short* base){
#define GLD1(i, OFF) asm volatile("global_load_dwordx4 %0, %1, off offset:" #OFF " sc0 sc1" \
                                  : "=v"(a[i]) : "v"(base) : "memory");
  GLD1(0,0)   GLD1(1,64)  GLD1(2,128) GLD1(3,192)
  GLD1(4,256) GLD1(5,320) GLD1(6,384) GLD1(7,448)
  GLD1(8,512) GLD1(9,576) GLD1(10,640) GLD1(11,704)
  GLD1(12,768) GLD1(13,832) GLD1(14,896) GLD1(15,960)
#undef GLD1
}
__device__ inline void llc_store16(short* dst, u32x4 v){
  asm volatile("global_store_dwordx4 %0, %1, off sc0 sc1" :: "v"(dst), "v"(v) : "memory");
}
__device__ inline void llc_store_flag(uint32_t* dst, uint32_t v){
  asm volatile("global_store_dword %0, %1, off sc0 sc1" :: "v"(dst), "v"(v) : "memory");
}
__device__ inline void vm_drain(){
  asm volatile("s_waitcnt vmcnt(0)" ::: "memory");
}
__device__ inline bool lineok(const uint32_t* q){   // one 64B flag line: 16 slices
  u32x4 a0,a1,a2,a3;
  asm volatile("global_load_dwordx4 %0, %4, off sc0 sc1\n\t"
               "global_load_dwordx4 %1, %4, off offset:16 sc0 sc1\n\t"
               "global_load_dwordx4 %2, %4, off offset:32 sc0 sc1\n\t"
               "global_load_dwordx4 %3, %4, off offset:48 sc0 sc1\n\t"
               "s_waitcnt vmcnt(0)"
               : "=v"(a0),"=v"(a1),"=v"(a2),"=v"(a3) : "v"(q) : "memory");
  u32x4 m = (a0 & a1) & (a2 & a3);
  return (m.x & m.y & m.z & m.w) == 0xFFFFFFFFu;
}

// ---------------- pipelined scan: 4 groups x 32 rows; L0/L1 WG pairs, flag-store sync ----------------
struct ScanP {
  const short* wrec;
  short *pub0, *pub1;                 // [ring4][128 rows][512 cols] bf16 each
  uint32_t *flgA, *flgB;              // [group4][t2048][16 slices] u32 (64B line per (g,t))
  const float *bh0,*bmup0,*bsgp0,*bh1,*bmup1,*bsgp1,*bout;
  const float *Am0,*As0,*E0,*Am1,*As1,*E1;
  float *out, *klpart;
};

__global__ __launch_bounds__(384, 1) void pvrnn_scan(ScanP P){
  extern __shared__ char smem[];
  short* ldsW  = (short*)smem;                   // up to 82 recs * 1KB        [0, 83968)
  short* zbS   = (short*)(smem + 83968);         // [3][32][72] bf16           [83968, 97792)
  float* muqS  = (float*)(smem + 97792);         // [3][32][64] f32            [97792, 122368)
  float* tqS   = (float*)(smem + 122368);        // [3][32][64] f32            [122368, 146944)
  short* dtile = (short*)(smem + 146944);        // [32][40] bf16 (padded)     [146944, 149504)
  float* mupT  = (float*)(smem + 149504);        // [32][4]
  float* tpT   = (float*)(smem + 150016);        // [32][4]
  float* xT    = (float*)(smem + 150528);        // [32][4]  (end 151040)

  const int p = blockIdx.x;
  const int xcd = p & 7;                          // locality heuristic ONLY (never correctness)
  const int g = xcd >> 1;                         // group on XCD pair
  const int role = xcd & 1;                       // 0=L0, 1=L1
  const int s = p >> 3;                           // slice 0..15
  const int wid = g*32 + role*16 + s;

  const int tid = threadIdx.x;
  const int l = tid & 63, w = tid >> 6;           // waves 0..3 recurrent (m=w&1,n=w>>1), 4..5 heads
  const int m = w & 1, n = w >> 1;
  const int c = l & 15, kb8 = (l >> 4) * 8;
  const int rowbase = 32*g + 16*m;
  const int CW = role ? 32 : 64;
  const int sh = role ? 5 : 6;

  { // weights -> LDS
    const u32x4* src = (const u32x4*)(P.wrec + (size_t)(role ? (832 + s*82) : (s*52)) * 512);
    const int n16 = (role ? 82 : 52) * 64;
    for (int i = tid; i < n16; i += 384) ((u32x4*)ldsW)[i] = src[i];
  }
  float bias_rec = 0.f, bias_head = 0.f;
  if (n < 2){
    bias_rec = role ? P.bh1[32*s + 16*n + c] : P.bh0[32*s + 16*n + c];
  } else {
    if (!role){
      if (c < 4)      bias_head = P.bmup0[4*s + c];
      else if (c < 8) bias_head = P.bsgp0[4*s + c - 4];
    } else {
      if (c < 2)      bias_head = P.bmup1[2*s + c];
      else if (c < 4) bias_head = P.bsgp1[2*s + c - 2];
      else if (c < 8) bias_head = P.bout [4*s + c - 4];
    }
  }
  const float* AM = role ? P.Am1 : P.Am0;
  const float* AS = role ? P.As1 : P.As0;
  const float* EP = role ? P.E1  : P.E0;

  auto do_stats = [&](int tt){                    // threads 64..383 (320 threads)
    const int par2 = tt % 3;
    const int NE = 32 << sh;
    for (int idx = tid - 64; idx < NE; idx += 320){
      int rr = idx >> sh, cc = idx & (CW - 1);
      size_t sidx = ((size_t)(32*g + rr) * 2048 + tt) * CW + cc;
      float mq = tanhf(AM[sidx]);
      float tq = tanhf(AS[sidx]);
      muqS[par2*2048 + rr*64 + cc] = mq;
      tqS [par2*2048 + rr*64 + cc] = tq;
      zbS [par2*2304 + rr*72 + cc] = (short)f2bf(fmaf(__expf(tq), EP[sidx], mq));
    }
  };
  if (w >= 1) do_stats(0);
  __syncthreads();

  float h[4] = {0.f,0.f,0.f,0.f};
  float klacc = 0.f;
  bool dead = false;
  const short* pubA = role ? P.pub1 : P.pub0;
  short* pubW = role ? P.pub1 : P.pub0;
  uint32_t* flgSelf = role ? P.flgB : P.flgA;
  const float leak = role ? 0.875f : 0.5f, gain = role ? 0.125f : 0.5f;

  for (int t = 0; t < 2048; ++t){
    // ---- dependency wait (tid0) overlapped with next-step stats (waves 1..5) ----
    if (tid == 0){
      const uint32_t *q1 = nullptr, *q2 = nullptr;   // q2 = gating (latest) flag
      if (!role){
        if (t >= 4) q1 = P.flgB + ((size_t)g*2048 + (t-4))*16;   // ring reuse safety
        if (t >= 1) q2 = P.flgA + ((size_t)g*2048 + (t-1))*16;   // own chain
      } else {
        q1 = P.flgA + ((size_t)g*2048 + t)*16;                    // d0(t) ready
        if (t >= 1) q2 = P.flgB + ((size_t)g*2048 + (t-1))*16;    // own chain
      }
      int it = 0;
      while (!dead && (q1 || q2)){
        if (q1 && lineok(q1)) q1 = nullptr;
        if (q2 && lineok(q2)) q2 = nullptr;
        if (!q1 && !q2) break;
        __builtin_amdgcn_s_sleep(1);
        if (++it > 3000000) dead = true;
      }
    } else if (w >= 1 && t + 1 < 2048){
      do_stats(t + 1);
    }
    __syncthreads();                              // B1

    const int par = t % 3;
    const short* A1 = pubA + (size_t)(((t-1)&3)*128 + rowbase) * 512;
    u32x4 af[16], ag[16];
    gld16(af, A1 + c*512 + kb8);
    if (role && n < 2){
      const short* A2 = P.pub0 + (size_t)((t&3)*128 + rowbase) * 512;
      gld16(ag, A2 + c*512 + kb8);
    }
    vm_drain();
    __builtin_amdgcn_sched_barrier(0);

    f32x4 av[4] = {{0.f,0.f,0.f,0.f},{0.f,0.f,0.f,0.f},{0.f,0.f,0.f,0.f},{0.f,0.f,0.f,0.f}};
    if (n < 2){
#pragma unroll
      for (int k = 0; k < 16; ++k){
        short8 b = *(const short8*)(ldsW + (n*16 + k)*512 + l*8);
        av[k&3] = __builtin_amdgcn_mfma_f32_16x16x32_bf16(*(const short8*)&af[k], b, av[k&3], 0,0,0);
      }
      if (role){
#pragma unroll
        for (int k = 0; k < 16; ++k){
          short8 b = *(const short8*)(ldsW + (48 + n*16 + k)*512 + l*8);
          av[k&3] = __builtin_amdgcn_mfma_f32_16x16x32_bf16(*(const short8*)&ag[k], b, av[k&3], 0,0,0);
        }
        short8 az = *(const short8*)(zbS + par*2304 + (16*m + c)*72 + kb8);
        short8 bz = *(const short8*)(ldsW + (80 + n)*512 + l*8);
        av[0] = __builtin_amdgcn_mfma_f32_16x16x32_bf16(az, bz, av[0], 0,0,0);
      } else {
        short8 az0 = *(const short8*)(zbS + par*2304 + (16*m + c)*72 + kb8);
        short8 az1 = *(const short8*)(zbS + par*2304 + (16*m + c)*72 + 32 + kb8);
        short8 bz0 = *(const short8*)(ldsW + (48 + n*2    )*512 + l*8);
        short8 bz1 = *(const short8*)(ldsW + (48 + n*2 + 1)*512 + l*8);
        av[0] = __builtin_amdgcn_mfma_f32_16x16x32_bf16(az0, bz0, av[0], 0,0,0);
        av[1] = __builtin_amdgcn_mfma_f32_16x16x32_bf16(az1, bz1, av[1], 0,0,0);
      }
    } else {
#pragma unroll
      for (int k = 0; k < 16; ++k){
        short8 b = *(const short8*)(ldsW + (32 + k)*512 + l*8);
        av[k&3] = __builtin_amdgcn_mfma_f32_16x16x32_bf16(*(const short8*)&af[k], b, av[k&3], 0,0,0);
      }
    }
    f32x4 acc = (av[0] + av[1]) + (av[2] + av[3]);

    // ---- epilogue ----
    if (n < 2){
#pragma unroll
      for (int j = 0; j < 4; ++j){
        float pre = acc[j] + bias_rec;
        h[j] = leak*h[j] + gain*pre;
        int row = 16*m + (l>>4)*4 + j;
        dtile[row*40 + 16*n + c] = (short)f2bf(tanhf(h[j]));
      }
    } else {
#pragma unroll
      for (int j = 0; j < 4; ++j){
        float pre = acc[j] + bias_head;
        int row = 16*m + (l>>4)*4 + j;
        if (!role){
          if (c < 4)      mupT[row*4 + c]     = tanhf(pre);
          else if (c < 8) tpT [row*4 + c - 4] = tanhf(pre);
        } else {
          if (c < 2)      mupT[row*4 + c]     = tanhf(pre);
          else if (c < 4) tpT [row*4 + c - 2] = tanhf(pre);
          else if (c < 8) xT  [row*4 + c - 4] = 1.f/(1.f + __expf(-pre));
        }
      }
    }
    __syncthreads();                              // B2

    if (w == 0){                                  // single-wave publish + wave-local flag
#pragma unroll
      for (int i2 = 0; i2 < 2; ++i2){
        int item = l + 64*i2;                     // 0..127 -> row 0..31, quarter 0..3
        int row = item >> 2, qq = item & 3;
        llc_store16(pubW + (size_t)((t&3)*128 + 32*g + row)*512 + 32*s + qq*8,
                    *(const u32x4*)(dtile + row*40 + qq*8));
      }
      vm_drain();                                 // data committed before flag
      if (l == 0)
        llc_store_flag(flgSelf + ((size_t)g*2048 + t)*16 + s, 0xFFFFFFFFu);
    } else if (w == 2 && l < 32){
      if (role && t >= 1)
        *(float4*)(P.out + ((size_t)(32*g + l)*2048 + (t-1))*64 + 4*s)
          = *(const float4*)(xT + l*4);
    } else if (w == 4 && l < 32){
      const int CC = role ? 2 : 4;
#pragma unroll
      for (int cc = 0; cc < 4; ++cc){
        if (cc < CC){
          float mp = mupT[l*4 + cc], tp = tpT[l*4 + cc];
          int zc = role ? (2*s + cc) : (4*s + cc);
          float mq = muqS[par*2048 + l*64 + zc];
          float tq = tqS [par*2048 + l*64 + zc];
          float dm = mq - mp;
          klacc += tp - tq + (__expf(2.f*tq) + dm*dm)*0.5f*__expf(-2.f*tp) - 0.5f;
        }
      }
    }
  }

  if (role){                                      // final x(2047) from d1(2047)
    if (tid == 0){
      const uint32_t* q = P.flgB + ((size_t)g*2048 + 2047)*16;
      int it = 0;
      while (!dead && !lineok(q)){
        __builtin_amdgcn_s_sleep(1);
        if (++it > 3000000) dead = true;
      }
    }
    __syncthreads();
    if (n == 2){
      const short* A1 = P.pub1 + (size_t)((2047&3)*128 + rowbase) * 512;
      u32x4 af[16];
      gld16(af, A1 + c*512 + kb8);
      vm_drain();
      __builtin_amdgcn_sched_barrier(0);
      f32x4 av[4] = {{0.f,0.f,0.f,0.f},{0.f,0.f,0.f,0.f},{0.f,0.f,0.f,0.f},{0.f,0.f,0.f,0.f}};
#pragma unroll
      for (int k = 0; k < 16; ++k){
        short8 b = *(const short8*)(ldsW + (32 + k)*512 + l*8);
        av[k&3] = __builtin_amdgcn_mfma_f32_16x16x32_bf16(*(const short8*)&af[k], b, av[k&3], 0,0,0);
      }
      f32x4 acc = (av[0] + av[1]) + (av[2] + av[3]);
#pragma unroll
      for (int j = 0; j < 4; ++j){
        if (c >= 4 && c < 8){
          int row = 16*m + (l>>4)*4 + j;
          xT[row*4 + c - 4] = 1.f/(1.f + __expf(-(acc[j] + bias_head)));
        }
      }
    }
    __syncthreads();
    if (w == 2 && l < 32)
      *(float4*)(P.out + ((size_t)(32*g + l)*2048 + 2047)*64 + 4*s)
        = *(const float4*)(xT + l*4);
  }

  if (w == 4){
    float v = klacc;
#pragma unroll
    for (int off = 32; off; off >>= 1) v += __shfl_down(v, off);
    if (l == 0) P.klpart[wid] = v;
  }
}

__global__ void kl_finalize(const float* __restrict__ klpart, float* __restrict__ out){
  if (blockIdx.x == 0 && threadIdx.x == 0){
    float k0 = 0.f, k1 = 0.f;
    for (int i = 0; i < 128; ++i){
      if ((i >> 4) & 1) k1 += klpart[i]; else k0 += klpart[i];
    }
    float kl = (k0 + k1) * (1.0f/128.0f);
    out[16777216] = kl;
    out[16777217] = 0.001f * kl;
  }
}

extern "C" void kernel_launch(void* const* d_in, const int* in_sizes, int n_in,
                              void* d_out, int out_size, void* d_ws, size_t ws_size,
                              hipStream_t stream){
  (void)in_sizes; (void)n_in; (void)out_size;
  const float* Wdh0  = (const float*)d_in[0];
  const float* Wzh0  = (const float*)d_in[1];
  const float* bh0   = (const float*)d_in[2];
  const float* Wmup0 = (const float*)d_in[3];
  const float* bmup0 = (const float*)d_in[4];
  const float* Wsgp0 = (const float*)d_in[5];
  const float* bsgp0 = (const float*)d_in[6];
  const float* Amu0  = (const float*)d_in[7];
  const float* Asg0  = (const float*)d_in[8];
  const float* Eps0  = (const float*)d_in[9];
  const float* Wdh1  = (const float*)d_in[10];
  const float* Wzh1  = (const float*)d_in[11];
  const float* Wih1  = (const float*)d_in[12];
  const float* bh1   = (const float*)d_in[13];
  const float* Wmup1 = (const float*)d_in[14];
  const float* bmup1 = (const float*)d_in[15];
  const float* Wsgp1 = (const float*)d_in[16];
  const float* bsgp1 = (const float*)d_in[17];
  const float* Amu1  = (const float*)d_in[18];
  const float* Asg1  = (const float*)d_in[19];
  const float* Eps1  = (const float*)d_in[20];
  const float* Wout  = (const float*)d_in[21];
  const float* bout  = (const float*)d_in[22];

  const size_t oW    = 0;                        // 2144 recs * 1KB = 2,195,456
  const size_t oPub0 = 2195456;                  // [4][128][512] bf16 = 512KB
  const size_t oPub1 = oPub0 + 524288;
  const size_t oFlgA = oPub1 + 524288;           // 4 groups * 2048 * 64B = 512KB
  const size_t oFlgB = oFlgA + 524288;
  const size_t oKL   = oFlgB + 524288;
  const size_t total = oKL + 512;
  if (ws_size < total) return;
  char* ws = (char*)d_ws;

  (void)hipMemsetAsync(ws + oPub0, 0, total - oPub0, stream);  // zero pubs + flags + klpart

  PreP pp;
  pp.Wdh0 = Wdh0; pp.Wzh0 = Wzh0; pp.Wmup0 = Wmup0; pp.Wsgp0 = Wsgp0;
  pp.Wdh1 = Wdh1; pp.Wzh1 = Wzh1; pp.Wih1 = Wih1; pp.Wmup1 = Wmup1;
  pp.Wsgp1 = Wsgp1; pp.Wout = Wout; pp.dst = (uint32_t*)(ws + oW);
  prepack<<<dim3(2144), dim3(64), 0, stream>>>(pp);

  ScanP sp;
  sp.wrec = (const short*)(ws + oW);
  sp.pub0 = (short*)(ws + oPub0);
  sp.pub1 = (short*)(ws + oPub1);
  sp.flgA = (uint32_t*)(ws + oFlgA);
  sp.flgB = (uint32_t*)(ws + oFlgB);
  sp.bh0 = bh0; sp.bmup0 = bmup0; sp.bsgp0 = bsgp0;
  sp.bh1 = bh1; sp.bmup1 = bmup1; sp.bsgp1 = bsgp1; sp.bout = bout;
  sp.Am0 = Amu0; sp.As0 = Asg0; sp.E0 = Eps0;
  sp.Am1 = Amu1; sp.As1 = Asg1; sp.E1 = Eps1;
  sp.out = (float*)d_out;
  sp.klpart = (float*)(ws + oKL);

  const unsigned SMEM = 151040u;
  (void)hipFuncSetAttribute((const void*)pvrnn_scan,
                            hipFuncAttributeMaxDynamicSharedMemorySize, 151040);
  void* args[] = { &sp };
  if (hipLaunchCooperativeKernel((void*)pvrnn_scan, dim3(128), dim3(384),
                                 args, SMEM, stream) != hipSuccess){
    pvrnn_scan<<<dim3(128), dim3(384), SMEM, stream>>>(sp);
  }
  kl_finalize<<<1, 1, 0, stream>>>((const float*)(ws + oKL), (float*)d_out);
}

// Round 11
// 16735.019 us; speedup vs baseline: 14.1053x; 1.5387x over previous
//
#include <hip/hip_runtime.h>
#include <stdint.h>

typedef float    f32x4  __attribute__((ext_vector_type(4)));
typedef short    short8 __attribute__((ext_vector_type(8)));
typedef uint32_t u32x4  __attribute__((ext_vector_type(4)));

__device__ inline uint16_t f2bf(float f){
  uint32_t u = __float_as_uint(f);
  u += 0x7fffu + ((u >> 16) & 1u);   // RNE
  return (uint16_t)(u >> 16);
}

// ---------------- prepack: weights -> per-WG MFMA B-fragment records ----------------
struct PreP {
  const float *Wdh0,*Wzh0,*Wmup0,*Wsgp0,*Wdh1,*Wzh1,*Wih1,*Wmup1,*Wsgp1,*Wout;
  uint32_t* dst;
};

__global__ __launch_bounds__(64) void prepack(PreP P){
  const int rec = blockIdx.x, l = threadIdx.x;
  int role, s, r;
  if (rec < 832){ role = 0; s = rec / 52; r = rec % 52; }
  else          { role = 1; int rr = rec - 832; s = rr / 82; r = rr % 82; }
  const int cl = l & 15, kb = (l >> 4) * 8;
  float v[8];
#pragma unroll
  for (int j = 0; j < 8; ++j) v[j] = 0.f;
  if (role == 0){
    if (r < 48){
      int n = r >> 4, k = r & 15, c = 16*n + cl, kk0 = k*32 + kb;
      if (c < 32){ int col = 32*s + c;
#pragma unroll
        for (int j = 0; j < 8; ++j) v[j] = P.Wdh0[(size_t)(kk0+j)*512 + col];
      } else if (c < 36){ int col = 4*s + (c-32);
#pragma unroll
        for (int j = 0; j < 8; ++j) v[j] = P.Wmup0[(size_t)(kk0+j)*64 + col];
      } else if (c < 40){ int col = 4*s + (c-36);
#pragma unroll
        for (int j = 0; j < 8; ++j) v[j] = P.Wsgp0[(size_t)(kk0+j)*64 + col];
      }
    } else {
      int r2 = r - 48, n = r2 >> 1, k = r2 & 1, col = 32*s + 16*n + cl, kk0 = k*32 + kb;
#pragma unroll
      for (int j = 0; j < 8; ++j) v[j] = P.Wzh0[(size_t)(kk0+j)*512 + col];
    }
  } else {
    if (r < 48){
      int n = r >> 4, k = r & 15, c = 16*n + cl, kk0 = k*32 + kb;
      if (c < 32){ int col = 32*s + c;
#pragma unroll
        for (int j = 0; j < 8; ++j) v[j] = P.Wdh1[(size_t)(kk0+j)*512 + col];
      } else if (c < 34){ int col = 2*s + (c-32);
#pragma unroll
        for (int j = 0; j < 8; ++j) v[j] = P.Wmup1[(size_t)(kk0+j)*32 + col];
      } else if (c < 36){ int col = 2*s + (c-34);
#pragma unroll
        for (int j = 0; j < 8; ++j) v[j] = P.Wsgp1[(size_t)(kk0+j)*32 + col];
      } else if (c < 40){ int col = 4*s + (c-36);
#pragma unroll
        for (int j = 0; j < 8; ++j) v[j] = P.Wout[(size_t)(kk0+j)*64 + col];
      }
    } else if (r < 80){
      int r2 = r - 48, n = r2 >> 4, k = r2 & 15, col = 32*s + 16*n + cl, kk0 = k*32 + kb;
#pragma unroll
      for (int j = 0; j < 8; ++j) v[j] = P.Wih1[(size_t)(kk0+j)*512 + col];
    } else {
      int n = r - 80, col = 32*s + 16*n + cl;
#pragma unroll
      for (int j = 0; j < 8; ++j) v[j] = P.Wzh1[(size_t)(kb+j)*512 + col];
    }
  }
  u32x4 o;
  o.x = (uint32_t)f2bf(v[0]) | ((uint32_t)f2bf(v[1]) << 16);
  o.y = (uint32_t)f2bf(v[2]) | ((uint32_t)f2bf(v[3]) << 16);
  o.z = (uint32_t)f2bf(v[4]) | ((uint32_t)f2bf(v[5]) << 16);
  o.w = (uint32_t)f2bf(v[6]) | ((uint32_t)f2bf(v[7]) << 16);
  ((u32x4*)(P.dst + (size_t)rec * 256))[l] = o;
}

// ---- device-coherent (LLC) transport: sc0 sc1 everywhere ----
__device__ inline void gld16(u32x4 (&a)[16], const short* base){
#define GLD1(i, OFF) asm volatile("global_load_dwordx4 %0, %1, off offset:" #OFF " sc0 sc1" \
                                  : "=v"(a[i]) : "v"(base) : "memory");
  GLD1(0,0)   GLD1(1,64)  GLD1(2,128) GLD1(3,192)
  GLD1(4,256) GLD1(5,320) GLD1(6,384) GLD1(7,448)
  GLD1(8,512) GLD1(9,576) GLD1(10,640) GLD1(11,704)
  GLD1(12,768) GLD1(13,832) GLD1(14,896) GLD1(15,960)
#undef GLD1
}
__device__ inline void llc_store16(short* dst, u32x4 v){
  asm volatile("global_store_dwordx4 %0, %1, off sc0 sc1" :: "v"(dst), "v"(v) : "memory");
}
__device__ inline void llc_store_flag(uint32_t* dst, uint32_t v){
  asm volatile("global_store_dword %0, %1, off sc0 sc1" :: "v"(dst), "v"(v) : "memory");
}
__device__ inline void vm_drain(){
  asm volatile("s_waitcnt vmcnt(0)" ::: "memory");
}
__device__ inline bool line64(const uint32_t* q){
  u32x4 a0,a1,a2,a3;
  asm volatile("global_load_dwordx4 %0, %4, off sc0 sc1\n\t"
               "global_load_dwordx4 %1, %4, off offset:16 sc0 sc1\n\t"
               "global_load_dwordx4 %2, %4, off offset:32 sc0 sc1\n\t"
               "global_load_dwordx4 %3, %4, off offset:48 sc0 sc1\n\t"
               "s_waitcnt vmcnt(0)"
               : "=v"(a0),"=v"(a1),"=v"(a2),"=v"(a3) : "v"(q) : "memory");
  u32x4 m = (a0 & a1) & (a2 & a3);
  return (m.x & m.y & m.z & m.w) == 0xFFFFFFFFu;
}
__device__ inline void line64x2(const uint32_t* qa, const uint32_t* qb, bool& oa, bool& ob){
  u32x4 a0,a1,a2,a3,b0,b1,b2,b3;
  asm volatile("global_load_dwordx4 %0, %8, off sc0 sc1\n\t"
               "global_load_dwordx4 %1, %8, off offset:16 sc0 sc1\n\t"
               "global_load_dwordx4 %2, %8, off offset:32 sc0 sc1\n\t"
               "global_load_dwordx4 %3, %8, off offset:48 sc0 sc1\n\t"
               "global_load_dwordx4 %4, %9, off sc0 sc1\n\t"
               "global_load_dwordx4 %5, %9, off offset:16 sc0 sc1\n\t"
               "global_load_dwordx4 %6, %9, off offset:32 sc0 sc1\n\t"
               "global_load_dwordx4 %7, %9, off offset:48 sc0 sc1\n\t"
               "s_waitcnt vmcnt(0)"
               : "=v"(a0),"=v"(a1),"=v"(a2),"=v"(a3),
                 "=v"(b0),"=v"(b1),"=v"(b2),"=v"(b3)
               : "v"(qa), "v"(qb) : "memory");
  u32x4 ma = (a0 & a1) & (a2 & a3);
  u32x4 mb = (b0 & b1) & (b2 & b3);
  oa = (ma.x & ma.y & ma.z & ma.w) == 0xFFFFFFFFu;
  ob = (mb.x & mb.y & mb.z & mb.w) == 0xFFFFFFFFu;
}

// stats pipeline: plain clamped loads (compiler-managed hazards), uniform count/role
#define ISSUE(NI, NE, SH, CWv, tt) do { \
  _Pragma("unroll") \
  for (int i = 0; i < (NI); ++i){ \
    int idx = (tid - 64) + 320*i; \
    int cidx = idx < (NE) ? idx : (NE)-1; \
    int rr = cidx >> (SH), cc = cidx & ((CWv)-1); \
    size_t sidx = ((size_t)(32*g + rr) * 2048 + (size_t)(tt)) * (CWv) + cc; \
    ra[i] = AM[sidx]; rsg[i] = AS[sidx]; rep[i] = EP[sidx]; \
  } \
} while(0)

#define PROCESS(NI, NE, SH, CWv, tt) do { \
  const int par2 = (tt) % 3; \
  _Pragma("unroll") \
  for (int i = 0; i < (NI); ++i){ \
    int idx = (tid - 64) + 320*i; \
    if (idx < (NE)){ \
      int rr = idx >> (SH), cc = idx & ((CWv)-1); \
      float mq = tanhf(ra[i]), tq = tanhf(rsg[i]); \
      muqS[par2*2048 + rr*64 + cc] = mq; \
      tqS [par2*2048 + rr*64 + cc] = tq; \
      zbS [par2*2304 + rr*72 + cc] = (short)f2bf(fmaf(__expf(tq), rep[i], mq)); \
    } \
  } \
} while(0)

// ---------------- pipelined scan: 4 groups x 32 rows; L0/L1 WG pairs ----------------
struct ScanP {
  const short* wrec;
  short *pub0, *pub1;                 // [ring4][128 rows][512 cols] bf16
  uint32_t *flgA, *flgB;              // [group4][t2048][16 slices] u32
  const float *bh0,*bmup0,*bsgp0,*bh1,*bmup1,*bsgp1,*bout;
  const float *Am0,*As0,*E0,*Am1,*As1,*E1;
  float *out, *klpart;
};

__global__ __launch_bounds__(384, 1) void pvrnn_scan(ScanP P){
  extern __shared__ char smem[];
  short* ldsW  = (short*)smem;                   // up to 82 recs * 1KB   [0, 83968)
  short* zbS   = (short*)(smem + 83968);         // [3][32][72] bf16
  float* muqS  = (float*)(smem + 97792);         // [3][32][64] f32
  float* tqS   = (float*)(smem + 122368);        // [3][32][64] f32
  short* dtile = (short*)(smem + 146944);        // [32][40] bf16
  float* mupT  = (float*)(smem + 149504);        // [32][4]
  float* tpT   = (float*)(smem + 150016);        // [32][4]
  float* xT    = (float*)(smem + 150528);        // [32][4]  (end 151040)

  const int p = blockIdx.x;
  const int xcd = p & 7;                          // locality heuristic ONLY
  const int g = xcd >> 1;
  const int role = xcd & 1;
  const int s = p >> 3;
  const int wid = g*32 + role*16 + s;

  const int tid = threadIdx.x;
  const int l = tid & 63, w = tid >> 6;           // waves 0..3 recurrent, 4..5 heads
  const int m = w & 1, n = w >> 1;
  const int c = l & 15, kb8 = (l >> 4) * 8;
  const int rowbase = 32*g + 16*m;

  { // weights -> LDS
    const u32x4* src = (const u32x4*)(P.wrec + (size_t)(role ? (832 + s*82) : (s*52)) * 512);
    const int n16 = (role ? 82 : 52) * 64;
    for (int i = tid; i < n16; i += 384) ((u32x4*)ldsW)[i] = src[i];
  }
  float bias_rec = 0.f, bias_head = 0.f;
  if (n < 2){
    bias_rec = role ? P.bh1[32*s + 16*n + c] : P.bh0[32*s + 16*n + c];
  } else {
    if (!role){
      if (c < 4)      bias_head = P.bmup0[4*s + c];
      else if (c < 8) bias_head = P.bsgp0[4*s + c - 4];
    } else {
      if (c < 2)      bias_head = P.bmup1[2*s + c];
      else if (c < 4) bias_head = P.bsgp1[2*s + c - 2];
      else if (c < 8) bias_head = P.bout [4*s + c - 4];
    }
  }
  const float* AM = role ? P.Am1 : P.Am0;
  const float* AS = role ? P.As1 : P.As0;
  const float* EP = role ? P.E1  : P.E0;
  const int CW = role ? 32 : 64;
  const int sh = role ? 5 : 6;

  float ra[7], rsg[7], rep[7];                    // stats prefetch registers

  if (tid >= 64){   // slot 0 direct, then issue loads for t=1
    const int NE = 32 << sh;
    for (int idx = tid - 64; idx < NE; idx += 320){
      int rr = idx >> sh, cc = idx & (CW - 1);
      size_t sidx = ((size_t)(32*g + rr) * 2048 + 0) * CW + cc;
      float mq = tanhf(AM[sidx]);
      float tq = tanhf(AS[sidx]);
      muqS[rr*64 + cc] = mq;
      tqS [rr*64 + cc] = tq;
      zbS [rr*72 + cc] = (short)f2bf(fmaf(__expf(tq), EP[sidx], mq));
    }
    if (!role) ISSUE(7, 2048, 6, 64, 1); else ISSUE(4, 1024, 5, 32, 1);
  }
  __syncthreads();

  float h[4] = {0.f,0.f,0.f,0.f};
  float klacc = 0.f;
  bool dead = false;
  const short* pubA = role ? P.pub1 : P.pub0;
  short* pubW = role ? P.pub1 : P.pub0;
  uint32_t* flgSelf = role ? P.flgB : P.flgA;
  const float leak = role ? 0.875f : 0.5f, gain = role ? 0.125f : 0.5f;

  for (int t = 0; t < 2048; ++t){
    // ---- poll (tid0) overlapped with stats-process (waves 1..5) ----
    if (tid == 0){
      const uint32_t *q1 = nullptr, *q2 = nullptr;
      if (!role){
        if (t >= 4) q1 = P.flgB + ((size_t)g*2048 + (t-4))*16;
        if (t >= 1) q2 = P.flgA + ((size_t)g*2048 + (t-1))*16;
      } else {
        q1 = P.flgA + ((size_t)g*2048 + t)*16;
        if (t >= 1) q2 = P.flgB + ((size_t)g*2048 + (t-1))*16;
      }
      int it = 0;
      while (!dead && (q1 || q2)){
        const uint32_t* A  = q1 ? q1 : q2;
        const uint32_t* B2 = q2 ? q2 : q1;
        bool okA, okB;
        line64x2(A, B2, okA, okB);
        if (q1 && okA) q1 = nullptr;
        if (q2 && okB) q2 = nullptr;
        if (!q1 && !q2) break;
        __builtin_amdgcn_s_sleep(1);
        if (++it > 3000000) dead = true;
      }
    } else if (tid >= 64 && t + 1 < 2048){
      if (!role) PROCESS(7, 2048, 6, 64, t+1); else PROCESS(4, 1024, 5, 32, t+1);
    }
    __syncthreads();                              // B1

    const int par = t % 3;
    const short* A1 = pubA + (size_t)(((t-1)&3)*128 + rowbase) * 512;
    u32x4 af[16], ag[16];
    gld16(af, A1 + c*512 + kb8);
    if (role && n < 2){
      const short* A2 = P.pub0 + (size_t)((t&3)*128 + rowbase) * 512;
      gld16(ag, A2 + c*512 + kb8);
    }
    // issue next-next-step stats loads AFTER af/ag (oldest = af/ag), then counted wait
    const bool issued = (tid >= 64) && (t + 2 < 2048);
    if (issued){
      if (!role) ISSUE(7, 2048, 6, 64, t+2); else ISSUE(4, 1024, 5, 32, t+2);
    }
    if (!issued)      vm_drain();                               // wave 0 / tail steps
    else if (!role)   asm volatile("s_waitcnt vmcnt(21)" ::: "memory");
    else              asm volatile("s_waitcnt vmcnt(12)" ::: "memory");
    __builtin_amdgcn_sched_barrier(0);

    f32x4 av[4] = {{0.f,0.f,0.f,0.f},{0.f,0.f,0.f,0.f},{0.f,0.f,0.f,0.f},{0.f,0.f,0.f,0.f}};
    if (n < 2){
#pragma unroll
      for (int k = 0; k < 16; ++k){
        short8 b = *(const short8*)(ldsW + (n*16 + k)*512 + l*8);
        av[k&3] = __builtin_amdgcn_mfma_f32_16x16x32_bf16(*(const short8*)&af[k], b, av[k&3], 0,0,0);
      }
      if (role){
#pragma unroll
        for (int k = 0; k < 16; ++k){
          short8 b = *(const short8*)(ldsW + (48 + n*16 + k)*512 + l*8);
          av[k&3] = __builtin_amdgcn_mfma_f32_16x16x32_bf16(*(const short8*)&ag[k], b, av[k&3], 0,0,0);
        }
        short8 az = *(const short8*)(zbS + par*2304 + (16*m + c)*72 + kb8);
        short8 bz = *(const short8*)(ldsW + (80 + n)*512 + l*8);
        av[0] = __builtin_amdgcn_mfma_f32_16x16x32_bf16(az, bz, av[0], 0,0,0);
      } else {
        short8 az0 = *(const short8*)(zbS + par*2304 + (16*m + c)*72 + kb8);
        short8 az1 = *(const short8*)(zbS + par*2304 + (16*m + c)*72 + 32 + kb8);
        short8 bz0 = *(const short8*)(ldsW + (48 + n*2    )*512 + l*8);
        short8 bz1 = *(const short8*)(ldsW + (48 + n*2 + 1)*512 + l*8);
        av[0] = __builtin_amdgcn_mfma_f32_16x16x32_bf16(az0, bz0, av[0], 0,0,0);
        av[1] = __builtin_amdgcn_mfma_f32_16x16x32_bf16(az1, bz1, av[1], 0,0,0);
      }
    } else {
#pragma unroll
      for (int k = 0; k < 16; ++k){
        short8 b = *(const short8*)(ldsW + (32 + k)*512 + l*8);
        av[k&3] = __builtin_amdgcn_mfma_f32_16x16x32_bf16(*(const short8*)&af[k], b, av[k&3], 0,0,0);
      }
    }
    f32x4 acc = (av[0] + av[1]) + (av[2] + av[3]);

    // ---- epilogue ----
    if (n < 2){
#pragma unroll
      for (int j = 0; j < 4; ++j){
        float pre = acc[j] + bias_rec;
        h[j] = leak*h[j] + gain*pre;
        int row = 16*m + (l>>4)*4 + j;
        dtile[row*40 + 16*n + c] = (short)f2bf(tanhf(h[j]));
      }
    } else {
#pragma unroll
      for (int j = 0; j < 4; ++j){
        float pre = acc[j] + bias_head;
        int row = 16*m + (l>>4)*4 + j;
        if (!role){
          if (c < 4)      mupT[row*4 + c]     = tanhf(pre);
          else if (c < 8) tpT [row*4 + c - 4] = tanhf(pre);
        } else {
          if (c < 2)      mupT[row*4 + c]     = tanhf(pre);
          else if (c < 4) tpT [row*4 + c - 2] = tanhf(pre);
          else if (c < 8) xT  [row*4 + c - 4] = 1.f/(1.f + __expf(-pre));
        }
      }
    }
    __syncthreads();                              // B2 (drains stats loads too)

    if (w == 0){                                  // single-wave publish + flag
#pragma unroll
      for (int i2 = 0; i2 < 2; ++i2){
        int item = l + 64*i2;
        int row = item >> 2, qq = item & 3;
        llc_store16(pubW + (size_t)((t&3)*128 + 32*g + row)*512 + 32*s + qq*8,
                    *(const u32x4*)(dtile + row*40 + qq*8));
      }
      vm_drain();                                 // data committed before flag
      if (l == 0)
        llc_store_flag(flgSelf + ((size_t)g*2048 + t)*16 + s, 0xFFFFFFFFu);
    } else if (w == 2 && l < 32){
      if (role && t >= 1)
        *(float4*)(P.out + ((size_t)(32*g + l)*2048 + (t-1))*64 + 4*s)
          = *(const float4*)(xT + l*4);
    } else if (w == 4 && l < 32){
      const int CC = role ? 2 : 4;
#pragma unroll
      for (int cc = 0; cc < 4; ++cc){
        if (cc < CC){
          float mp = mupT[l*4 + cc], tp = tpT[l*4 + cc];
          int zc = role ? (2*s + cc) : (4*s + cc);
          float mq = muqS[par*2048 + l*64 + zc];
          float tq = tqS [par*2048 + l*64 + zc];
          float dm = mq - mp;
          klacc += tp - tq + (__expf(2.f*tq) + dm*dm)*0.5f*__expf(-2.f*tp) - 0.5f;
        }
      }
    }
  }

  if (role){                                      // final x(2047)
    if (tid == 0){
      const uint32_t* q = P.flgB + ((size_t)g*2048 + 2047)*16;
      int it = 0;
      while (!dead && !line64(q)){
        __builtin_amdgcn_s_sleep(1);
        if (++it > 3000000) dead = true;
      }
    }
    __syncthreads();
    if (n == 2){
      const short* A1 = P.pub1 + (size_t)((2047&3)*128 + rowbase) * 512;
      u32x4 af[16];
      gld16(af, A1 + c*512 + kb8);
      vm_drain();
      __builtin_amdgcn_sched_barrier(0);
      f32x4 av[4] = {{0.f,0.f,0.f,0.f},{0.f,0.f,0.f,0.f},{0.f,0.f,0.f,0.f},{0.f,0.f,0.f,0.f}};
#pragma unroll
      for (int k = 0; k < 16; ++k){
        short8 b = *(const short8*)(ldsW + (32 + k)*512 + l*8);
        av[k&3] = __builtin_amdgcn_mfma_f32_16x16x32_bf16(*(const short8*)&af[k], b, av[k&3], 0,0,0);
      }
      f32x4 acc = (av[0] + av[1]) + (av[2] + av[3]);
#pragma unroll
      for (int j = 0; j < 4; ++j){
        if (c >= 4 && c < 8){
          int row = 16*m + (l>>4)*4 + j;
          xT[row*4 + c - 4] = 1.f/(1.f + __expf(-(acc[j] + bias_head)));
        }
      }
    }
    __syncthreads();
    if (w == 2 && l < 32)
      *(float4*)(P.out + ((size_t)(32*g + l)*2048 + 2047)*64 + 4*s)
        = *(const float4*)(xT + l*4);
  }

  if (w == 4){
    float v = klacc;
#pragma unroll
    for (int off = 32; off; off >>= 1) v += __shfl_down(v, off);
    if (l == 0) P.klpart[wid] = v;
  }
}

__global__ void kl_finalize(const float* __restrict__ klpart, float* __restrict__ out){
  if (blockIdx.x == 0 && threadIdx.x == 0){
    float k0 = 0.f, k1 = 0.f;
    for (int i = 0; i < 128; ++i){
      if ((i >> 4) & 1) k1 += klpart[i]; else k0 += klpart[i];
    }
    float kl = (k0 + k1) * (1.0f/128.0f);
    out[16777216] = kl;
    out[16777217] = 0.001f * kl;
  }
}

extern "C" void kernel_launch(void* const* d_in, const int* in_sizes, int n_in,
                              void* d_out, int out_size, void* d_ws, size_t ws_size,
                              hipStream_t stream){
  (void)in_sizes; (void)n_in; (void)out_size;
  const float* Wdh0  = (const float*)d_in[0];
  const float* Wzh0  = (const float*)d_in[1];
  const float* bh0   = (const float*)d_in[2];
  const float* Wmup0 = (const float*)d_in[3];
  const float* bmup0 = (const float*)d_in[4];
  const float* Wsgp0 = (const float*)d_in[5];
  const float* bsgp0 = (const float*)d_in[6];
  const float* Amu0  = (const float*)d_in[7];
  const float* Asg0  = (const float*)d_in[8];
  const float* Eps0  = (const float*)d_in[9];
  const float* Wdh1  = (const float*)d_in[10];
  const float* Wzh1  = (const float*)d_in[11];
  const float* Wih1  = (const float*)d_in[12];
  const float* bh1   = (const float*)d_in[13];
  const float* Wmup1 = (const float*)d_in[14];
  const float* bmup1 = (const float*)d_in[15];
  const float* Wsgp1 = (const float*)d_in[16];
  const float* bsgp1 = (const float*)d_in[17];
  const float* Amu1  = (const float*)d_in[18];
  const float* Asg1  = (const float*)d_in[19];
  const float* Eps1  = (const float*)d_in[20];
  const float* Wout  = (const float*)d_in[21];
  const float* bout  = (const float*)d_in[22];

  const size_t oW    = 0;                        // 2144 recs * 1KB
  const size_t oPub0 = 2195456;                  // [4][128][512] bf16 = 512KB
  const size_t oPub1 = oPub0 + 524288;
  const size_t oFlgA = oPub1 + 524288;           // 4 groups * 2048 * 64B = 512KB
  const size_t oFlgB = oFlgA + 524288;
  const size_t oKL   = oFlgB + 524288;
  const size_t total = oKL + 512;
  if (ws_size < total) return;
  char* ws = (char*)d_ws;

  (void)hipMemsetAsync(ws + oPub0, 0, total - oPub0, stream);

  PreP pp;
  pp.Wdh0 = Wdh0; pp.Wzh0 = Wzh0; pp.Wmup0 = Wmup0; pp.Wsgp0 = Wsgp0;
  pp.Wdh1 = Wdh1; pp.Wzh1 = Wzh1; pp.Wih1 = Wih1; pp.Wmup1 = Wmup1;
  pp.Wsgp1 = Wsgp1; pp.Wout = Wout; pp.dst = (uint32_t*)(ws + oW);
  prepack<<<dim3(2144), dim3(64), 0, stream>>>(pp);

  ScanP sp;
  sp.wrec = (const short*)(ws + oW);
  sp.pub0 = (short*)(ws + oPub0);
  sp.pub1 = (short*)(ws + oPub1);
  sp.flgA = (uint32_t*)(ws + oFlgA);
  sp.flgB = (uint32_t*)(ws + oFlgB);
  sp.bh0 = bh0; sp.bmup0 = bmup0; sp.bsgp0 = bsgp0;
  sp.bh1 = bh1; sp.bmup1 = bmup1; sp.bsgp1 = bsgp1; sp.bout = bout;
  sp.Am0 = Amu0; sp.As0 = Asg0; sp.E0 = Eps0;
  sp.Am1 = Amu1; sp.As1 = Asg1; sp.E1 = Eps1;
  sp.out = (float*)d_out;
  sp.klpart = (float*)(ws + oKL);

  const unsigned SMEM = 151040u;
  (void)hipFuncSetAttribute((const void*)pvrnn_scan,
                            hipFuncAttributeMaxDynamicSharedMemorySize, 151040);
  void* args[] = { &sp };
  if (hipLaunchCooperativeKernel((void*)pvrnn_scan, dim3(128), dim3(384),
                                 args, SMEM, stream) != hipSuccess){
    pvrnn_scan<<<dim3(128), dim3(384), SMEM, stream>>>(sp);
  }
  kl_finalize<<<1, 1, 0, stream>>>((const float*)(ws + oKL), (float*)d_out);
}